// Round 7
// baseline (226.984 us; speedup 1.0000x reference)
//
#include <hip/hip_runtime.h>
#include <math.h>

#define EDIM 128
#define BB   256
#define SS   512
#define NWAVE 16
#define BLOCK (NWAVE * 64)
#define NPART 2            // parts (blocks) per batch row
#define TPG   4            // tokens per 16-lane group

// ws float layout: M[512] | Z[512] | A[512][128] | flags[256] (ints)
#define WS_M    0
#define WS_Z    512
#define WS_A    1024
#define WS_FLAG 66560      // float offset; byte offset 266240

// DPP-based add: runs on VALU, keeps the DS pipe free.
template<int CTRL>
__device__ __forceinline__ float dpp_add(float v) {
    int r = __builtin_amdgcn_update_dpp(0, __float_as_int(v), CTRL, 0xF, 0xF, true);
    return v + __int_as_float(r);
}

// Sum across the 16 lanes of a DPP row (all 16 lanes get the total).
__device__ __forceinline__ float rowsum16(float v) {
    v = dpp_add<0xB1>(v);    // quad_perm xor1
    v = dpp_add<0x4E>(v);    // quad_perm xor2
    v = dpp_add<0x124>(v);   // row_ror:4
    v = dpp_add<0x128>(v);   // row_ror:8
    return v;
}

// NOTE: no min-waves clause — R6 showed __launch_bounds__(1024,8) forces a
// 32-VGPR cap -> 84 MB scratch spill. Natural allocation (~40-56 VGPR) gets
// 2 blocks/CU (32 waves/CU) on its own.
__global__ __launch_bounds__(BLOCK)
void fused_embed_attn_fused(const int* __restrict__ x,
                            const float* __restrict__ emb,
                            const float* __restrict__ Wq,
                            const float* __restrict__ bq,
                            const float* __restrict__ Wm,
                            const float* __restrict__ bm,
                            float* __restrict__ ws,
                            float* __restrict__ out)
{
    const int part = blockIdx.x;          // 0..511
    const int b    = part >> 1;
    const int half = part & 1;
    const int tid  = threadIdx.x;
    const int wave = tid >> 6;
    const int lane = tid & 63;
    const int row  = lane >> 4;           // 4 groups per wave
    const int slot = lane & 15;           // 16 lanes per token
    const int d0   = slot * 8;            // 8 dims per lane

    const float4 wq0 = *reinterpret_cast<const float4*>(Wq + d0);
    const float4 wq1 = *reinterpret_cast<const float4*>(Wq + d0 + 4);
    const float  bq0 = bq[0];

    // group owns TPG=4 consecutive tokens
    const int g     = wave * 4 + row;                 // 0..63
    const int tbase = b * SS + half * 256 + g * TPG;
    const int4 iv   = *reinterpret_cast<const int4*>(x + tbase);
    const int idx[TPG] = {iv.x, iv.y, iv.z, iv.w};

    // serial online-softmax (keeps VGPR low; TLP hides latency at 32 waves/CU)
    float m = -INFINITY, Z = 0.f;
    float acc[8] = {0.f, 0.f, 0.f, 0.f, 0.f, 0.f, 0.f, 0.f};

    #pragma unroll
    for (int i = 0; i < TPG; ++i) {
        const float* rp = emb + (size_t)idx[i] * EDIM + d0;
        const float4 e0 = *reinterpret_cast<const float4*>(rp);
        const float4 e1 = *reinterpret_cast<const float4*>(rp + 4);

        float q = e0.x * wq0.x + e0.y * wq0.y + e0.z * wq0.z + e0.w * wq0.w
                + e1.x * wq1.x + e1.y * wq1.y + e1.z * wq1.z + e1.w * wq1.w;
        float s = e0.x + e0.y + e0.z + e0.w + e1.x + e1.y + e1.z + e1.w;
        q = rowsum16(q);
        s = rowsum16(s);
        const float lp = (q + bq0) * s;

        const float mn = fmaxf(m, lp);
        const float al = __expf(m - mn);   // m=-inf first iter -> 0
        const float w  = __expf(lp - mn);
        Z = Z * al + w;
        acc[0] = acc[0] * al + w * e0.x;  acc[1] = acc[1] * al + w * e0.y;
        acc[2] = acc[2] * al + w * e0.z;  acc[3] = acc[3] * al + w * e0.w;
        acc[4] = acc[4] * al + w * e1.x;  acc[5] = acc[5] * al + w * e1.y;
        acc[6] = acc[6] * al + w * e1.z;  acc[7] = acc[7] * al + w * e1.w;
        m = mn;
    }

    // merge the wave's 4 row-groups (cross-row shuffles, once)
    float m1 = fmaxf(m, __shfl_xor(m, 16));
    const float M  = fmaxf(m1, __shfl_xor(m1, 32));
    const float sc = __expf(m - M);
    float Zs = Z * sc;
    Zs += __shfl_xor(Zs, 16);
    Zs += __shfl_xor(Zs, 32);
    #pragma unroll
    for (int j = 0; j < 8; ++j) {
        float a = acc[j] * sc;
        a += __shfl_xor(a, 16);
        a += __shfl_xor(a, 32);
        acc[j] = a;
    }

    // block merge of the 16 wave partials (pad stride to 132 floats)
    __shared__ float sm[NWAVE];
    __shared__ float szv[NWAVE];
    __shared__ float sacc[NWAVE][EDIM + 4];

    if (row == 0) {
        *reinterpret_cast<float4*>(&sacc[wave][d0])     = make_float4(acc[0], acc[1], acc[2], acc[3]);
        *reinterpret_cast<float4*>(&sacc[wave][d0 + 4]) = make_float4(acc[4], acc[5], acc[6], acc[7]);
        if (slot == 0) { sm[wave] = M; szv[wave] = Zs; }
    }
    __syncthreads();

    if (tid < EDIM) {
        float Mb = sm[0];
        #pragma unroll
        for (int w = 1; w < NWAVE; ++w) Mb = fmaxf(Mb, sm[w]);
        float zt = 0.f, tv = 0.f;
        #pragma unroll
        for (int w = 0; w < NWAVE; ++w) {
            const float s2 = __expf(sm[w] - Mb);
            zt += szv[w] * s2;
            tv += sacc[w][tid] * s2;
        }
        ws[WS_A + part * EDIM + tid] = tv;      // unnormalized, referenced to Mb
        if (tid == 0) { ws[WS_M + part] = Mb; ws[WS_Z + part] = zt; }
    }
    __syncthreads();

    // ---- last-block-per-row merge (single launch, no second kernel) ----
    __shared__ int s_win;
    if (tid == 0) {
        __threadfence();                          // release our partial
        int* flags = reinterpret_cast<int*>(ws) + WS_FLAG;
        const int old = atomicAdd(&flags[b], 1);  // device-scope
        s_win = (old == NPART - 1);
    }
    __syncthreads();
    if (!s_win) return;
    __threadfence();                              // acquire partner's partial

    if (tid < 64) {
        const float m0 = ws[WS_M + b * 2],  m1v = ws[WS_M + b * 2 + 1];
        const float z0 = ws[WS_Z + b * 2],  z1v = ws[WS_Z + b * 2 + 1];
        const float Mx = fmaxf(m0, m1v);
        const float s0 = __expf(m0 - Mx);
        const float s1 = __expf(m1v - Mx);
        const float zt = z0 * s0 + z1v * s1;

        const float2 a0 = *reinterpret_cast<const float2*>(ws + WS_A + (b * 2)     * EDIM + 2 * tid);
        const float2 a1 = *reinterpret_cast<const float2*>(ws + WS_A + (b * 2 + 1) * EDIM + 2 * tid);
        const float t0 = (a0.x * s0 + a1.x * s1) / zt;
        const float t1 = (a0.y * s0 + a1.y * s1) / zt;

        const float4 wm = *reinterpret_cast<const float4*>(Wm + 4 * tid);
        float c0 = t0 * wm.x + t1 * wm.z;
        float c1 = t0 * wm.y + t1 * wm.w;
        #pragma unroll
        for (int off = 32; off >= 1; off >>= 1) {
            c0 += __shfl_xor(c0, off);
            c1 += __shfl_xor(c1, off);
        }
        if (tid == 0) {
            out[b * 2 + 0] = fmaxf(c0 + bm[0], 0.f);
            out[b * 2 + 1] = fmaxf(c1 + bm[1], 0.f);
        }
    }
}

extern "C" void kernel_launch(void* const* d_in, const int* in_sizes, int n_in,
                              void* d_out, int out_size, void* d_ws, size_t ws_size,
                              hipStream_t stream) {
    const int*   x   = (const int*)  d_in[0];
    const float* emb = (const float*)d_in[1];
    const float* Wq  = (const float*)d_in[2];
    const float* bq  = (const float*)d_in[3];
    const float* Wm  = (const float*)d_in[4];
    const float* bm  = (const float*)d_in[5];
    float* out = (float*)d_out;
    float* ws  = (float*)d_ws;   // needs (66560 + 256)*4 ≈ 267 KB

    // zero the per-row arrival flags (poisoned to 0xAA before every launch)
    hipMemsetAsync((char*)d_ws + WS_FLAG * sizeof(float), 0,
                   BB * sizeof(int), stream);

    hipLaunchKernelGGL(fused_embed_attn_fused, dim3(NPART * BB), dim3(BLOCK), 0,
                       stream, x, emb, Wq, bq, Wm, bm, ws, out);
}

// Round 8
// 99.654 us; speedup vs baseline: 2.2777x; 2.2777x over previous
//
#include <hip/hip_runtime.h>
#include <math.h>

#define EDIM 128
#define BB   256
#define SS   512
#define NWAVE 16
#define BLOCK (NWAVE * 64)
#define TPG   4            // tokens per 16-lane group (256 tokens / 64 groups)

// ws float layout: M[512] | Z[512] | A[512][128]
#define WS_M 0
#define WS_Z 512
#define WS_A 1024

// DPP-based add: runs on VALU, keeps the DS pipe free.
template<int CTRL>
__device__ __forceinline__ float dpp_add(float v) {
    int r = __builtin_amdgcn_update_dpp(0, __float_as_int(v), CTRL, 0xF, 0xF, true);
    return v + __int_as_float(r);
}

// Sum across the 16 lanes of a DPP row (all 16 lanes get the total).
__device__ __forceinline__ float rowsum16(float v) {
    v = dpp_add<0xB1>(v);    // quad_perm xor1
    v = dpp_add<0x4E>(v);    // quad_perm xor2
    v = dpp_add<0x124>(v);   // row_ror:4
    v = dpp_add<0x128>(v);   // row_ror:8
    return v;
}

// Phase 1: 512 blocks, each = half a batch row. 2 blocks/CU -> 32 waves/CU.
// NO min-waves clause (R6: it forced 32 VGPR -> 84 MB scratch spill).
__global__ __launch_bounds__(BLOCK)
void partial_kernel(const int* __restrict__ x,
                    const float* __restrict__ emb,
                    const float* __restrict__ Wq,
                    const float* __restrict__ bq,
                    float* __restrict__ ws)
{
    const int part = blockIdx.x;          // 0..511
    const int b    = part >> 1;
    const int half = part & 1;
    const int tid  = threadIdx.x;
    const int wave = tid >> 6;
    const int lane = tid & 63;
    const int row  = lane >> 4;           // 4 groups per wave
    const int slot = lane & 15;           // 16 lanes per token
    // contiguous-16B-per-lane layout: lane owns dims [4s,4s+4) and [64+4s,64+4s+4)
    const int dA   = slot * 4;
    const int dB   = 64 + slot * 4;

    const float4 wq0 = *reinterpret_cast<const float4*>(Wq + dA);
    const float4 wq1 = *reinterpret_cast<const float4*>(Wq + dB);
    const float  bq0 = bq[0];

    // group owns TPG=4 consecutive tokens
    const int g     = wave * 4 + row;                 // 0..63
    const int tbase = b * SS + half * 256 + g * TPG;
    const int4 iv   = *reinterpret_cast<const int4*>(x + tbase);
    const int idx[TPG] = {iv.x, iv.y, iv.z, iv.w};

    // serial online-softmax (low VGPR; TLP at 32 waves/CU hides latency)
    float m = -INFINITY, Z = 0.f;
    float acc[8] = {0.f, 0.f, 0.f, 0.f, 0.f, 0.f, 0.f, 0.f};

    #pragma unroll
    for (int i = 0; i < TPG; ++i) {
        const float* rp = emb + (size_t)idx[i] * EDIM;
        const float4 e0 = *reinterpret_cast<const float4*>(rp + dA);
        const float4 e1 = *reinterpret_cast<const float4*>(rp + dB);

        float q = e0.x * wq0.x + e0.y * wq0.y + e0.z * wq0.z + e0.w * wq0.w
                + e1.x * wq1.x + e1.y * wq1.y + e1.z * wq1.z + e1.w * wq1.w;
        float s = e0.x + e0.y + e0.z + e0.w + e1.x + e1.y + e1.z + e1.w;
        q = rowsum16(q);
        s = rowsum16(s);
        const float lp = (q + bq0) * s;

        const float mn = fmaxf(m, lp);
        const float al = __expf(m - mn);   // m=-inf first iter -> 0
        const float w  = __expf(lp - mn);
        Z = Z * al + w;
        acc[0] = acc[0] * al + w * e0.x;  acc[1] = acc[1] * al + w * e0.y;
        acc[2] = acc[2] * al + w * e0.z;  acc[3] = acc[3] * al + w * e0.w;
        acc[4] = acc[4] * al + w * e1.x;  acc[5] = acc[5] * al + w * e1.y;
        acc[6] = acc[6] * al + w * e1.z;  acc[7] = acc[7] * al + w * e1.w;
        m = mn;
    }

    // merge the wave's 4 row-groups (cross-row shuffles, once)
    float m1 = fmaxf(m, __shfl_xor(m, 16));
    const float M  = fmaxf(m1, __shfl_xor(m1, 32));
    const float sc = __expf(m - M);
    float Zs = Z * sc;
    Zs += __shfl_xor(Zs, 16);
    Zs += __shfl_xor(Zs, 32);
    #pragma unroll
    for (int j = 0; j < 8; ++j) {
        float a = acc[j] * sc;
        a += __shfl_xor(a, 16);
        a += __shfl_xor(a, 32);
        acc[j] = a;
    }

    // block merge of the 16 wave partials
    __shared__ float sm[NWAVE];
    __shared__ float szv[NWAVE];
    __shared__ float sacc[NWAVE][EDIM];

    if (row == 0) {
        *reinterpret_cast<float4*>(&sacc[wave][dA]) = make_float4(acc[0], acc[1], acc[2], acc[3]);
        *reinterpret_cast<float4*>(&sacc[wave][dB]) = make_float4(acc[4], acc[5], acc[6], acc[7]);
        if (slot == 0) { sm[wave] = M; szv[wave] = Zs; }
    }
    __syncthreads();

    if (tid < EDIM) {
        float Mb = sm[0];
        #pragma unroll
        for (int w = 1; w < NWAVE; ++w) Mb = fmaxf(Mb, sm[w]);
        float zt = 0.f, tv = 0.f;
        #pragma unroll
        for (int w = 0; w < NWAVE; ++w) {
            const float s2 = __expf(sm[w] - Mb);
            zt += szv[w] * s2;
            tv += sacc[w][tid] * s2;
        }
        ws[WS_A + part * EDIM + tid] = tv;     // unnormalized, referenced to Mb
        if (tid == 0) { ws[WS_M + part] = Mb; ws[WS_Z + part] = zt; }
    }
}

// Phase 2: merge halves + project + relu (reads in fixed part order -> deterministic)
__global__ __launch_bounds__(64)
void merge_kernel(const float* __restrict__ ws,
                  const float* __restrict__ Wm,
                  const float* __restrict__ bm,
                  float* __restrict__ out)
{
    const int b    = blockIdx.x;
    const int lane = threadIdx.x;

    const float m0 = ws[WS_M + b * 2],  m1 = ws[WS_M + b * 2 + 1];
    const float z0 = ws[WS_Z + b * 2],  z1 = ws[WS_Z + b * 2 + 1];
    const float M  = fmaxf(m0, m1);
    const float s0 = __expf(m0 - M);
    const float s1 = __expf(m1 - M);
    const float zt = z0 * s0 + z1 * s1;

    const float2 a0 = *reinterpret_cast<const float2*>(ws + WS_A + (b * 2)     * EDIM + 2 * lane);
    const float2 a1 = *reinterpret_cast<const float2*>(ws + WS_A + (b * 2 + 1) * EDIM + 2 * lane);
    const float t0 = (a0.x * s0 + a1.x * s1) / zt;
    const float t1 = (a0.y * s0 + a1.y * s1) / zt;

    const float4 wm = *reinterpret_cast<const float4*>(Wm + 4 * lane);
    float c0 = t0 * wm.x + t1 * wm.z;
    float c1 = t0 * wm.y + t1 * wm.w;
    #pragma unroll
    for (int off = 32; off >= 1; off >>= 1) {
        c0 += __shfl_xor(c0, off);
        c1 += __shfl_xor(c1, off);
    }
    if (lane == 0) {
        out[b * 2 + 0] = fmaxf(c0 + bm[0], 0.f);
        out[b * 2 + 1] = fmaxf(c1 + bm[1], 0.f);
    }
}

extern "C" void kernel_launch(void* const* d_in, const int* in_sizes, int n_in,
                              void* d_out, int out_size, void* d_ws, size_t ws_size,
                              hipStream_t stream) {
    const int*   x   = (const int*)  d_in[0];
    const float* emb = (const float*)d_in[1];
    const float* Wq  = (const float*)d_in[2];
    const float* bq  = (const float*)d_in[3];
    const float* Wm  = (const float*)d_in[4];
    const float* bm  = (const float*)d_in[5];
    float* out = (float*)d_out;
    float* ws  = (float*)d_ws;   // needs (1024 + 512*128)*4 = 266 KB

    hipLaunchKernelGGL(partial_kernel, dim3(2 * BB), dim3(BLOCK), 0, stream,
                       x, emb, Wq, bq, ws);
    hipLaunchKernelGGL(merge_kernel, dim3(BB), dim3(64), 0, stream,
                       ws, Wm, bm, out);
}

// Round 9
// 97.457 us; speedup vs baseline: 2.3291x; 1.0225x over previous
//
#include <hip/hip_runtime.h>
#include <math.h>

#define VOCAB 100000
#define EDIM  128
#define BB    256
#define SS    512

// DPP-based add: runs on VALU, keeps the DS pipe free.
template<int CTRL>
__device__ __forceinline__ float dpp_add(float v) {
    int r = __builtin_amdgcn_update_dpp(0, __float_as_int(v), CTRL, 0xF, 0xF, true);
    return v + __int_as_float(r);
}

// Sum across the 16 lanes of a DPP row (all 16 lanes get the total).
__device__ __forceinline__ float rowsum16(float v) {
    v = dpp_add<0xB1>(v);    // quad_perm xor1
    v = dpp_add<0x4E>(v);    // quad_perm xor2
    v = dpp_add<0x124>(v);   // row_ror:4
    v = dpp_add<0x128>(v);   // row_ror:8
    return v;
}

// ---- Kernel A: stream emb once (coalesced), emit 4 scalars per vocab row ----
// tab[v] = { q_v = emb[v].Wq,  s_v = sum(emb[v]),
//            m0_v = emb[v].Wm[:,0],  m1_v = emb[v].Wm[:,1] }
__global__ __launch_bounds__(1024)
void precompute_tab(const float* __restrict__ emb,
                    const float* __restrict__ Wq,
                    const float* __restrict__ Wm,
                    float4* __restrict__ tab)
{
    const int tid  = threadIdx.x;
    const int wave = tid >> 6;
    const int lane = tid & 63;
    const int row  = lane >> 4;           // 4 rows per wave
    const int slot = lane & 15;           // 16 lanes per row
    const int v    = blockIdx.x * 64 + wave * 4 + row;
    if (v >= VOCAB) return;

    const int dA = slot * 4;              // dims [4s, 4s+4)
    const int dB = 64 + slot * 4;         // dims [64+4s, 64+4s+4)

    const float* rp = emb + (size_t)v * EDIM;
    const float4 e0 = *reinterpret_cast<const float4*>(rp + dA);
    const float4 e1 = *reinterpret_cast<const float4*>(rp + dB);

    const float4 wq0 = *reinterpret_cast<const float4*>(Wq + dA);
    const float4 wq1 = *reinterpret_cast<const float4*>(Wq + dB);
    // Wm is [E,2] row-major: interleaved (col0,col1) pairs
    const float4 wA0 = *reinterpret_cast<const float4*>(Wm + 2 * dA);
    const float4 wA1 = *reinterpret_cast<const float4*>(Wm + 2 * dA + 4);
    const float4 wB0 = *reinterpret_cast<const float4*>(Wm + 2 * dB);
    const float4 wB1 = *reinterpret_cast<const float4*>(Wm + 2 * dB + 4);

    float q  = e0.x * wq0.x + e0.y * wq0.y + e0.z * wq0.z + e0.w * wq0.w
             + e1.x * wq1.x + e1.y * wq1.y + e1.z * wq1.z + e1.w * wq1.w;
    float s  = e0.x + e0.y + e0.z + e0.w + e1.x + e1.y + e1.z + e1.w;
    float m0 = e0.x * wA0.x + e0.y * wA0.z + e0.z * wA1.x + e0.w * wA1.z
             + e1.x * wB0.x + e1.y * wB0.z + e1.z * wB1.x + e1.w * wB1.z;
    float m1 = e0.x * wA0.y + e0.y * wA0.w + e0.z * wA1.y + e0.w * wA1.w
             + e1.x * wB0.y + e1.y * wB0.w + e1.z * wB1.y + e1.w * wB1.w;

    q  = rowsum16(q);
    s  = rowsum16(s);
    m0 = rowsum16(m0);
    m1 = rowsum16(m1);

    if (slot == 0) tab[v] = make_float4(q, s, m0, m1);
}

// ---- Kernel B: per batch row, softmax over S and weighted sums of (m0,m1) ----
__global__ __launch_bounds__(SS)
void attn_out(const int* __restrict__ x,
              const float4* __restrict__ tab,
              const float* __restrict__ bq,
              const float* __restrict__ bm,
              float* __restrict__ out)
{
    const int b    = blockIdx.x;
    const int t    = threadIdx.x;         // 512 threads = 1 token each
    const int wave = t >> 6;
    const int lane = t & 63;

    const float4 ts = tab[x[b * SS + t]]; // 16-B gather from 1.6 MB hot table
    const float lp  = (ts.x + bq[0]) * ts.y;

    // block max over 512
    float m = lp;
    #pragma unroll
    for (int off = 32; off >= 1; off >>= 1) m = fmaxf(m, __shfl_xor(m, off));

    __shared__ float sred[8][4];
    if (lane == 0) sred[wave][0] = m;
    __syncthreads();
    float M = sred[0][0];
    #pragma unroll
    for (int w = 1; w < 8; ++w) M = fmaxf(M, sred[w][0]);

    const float wgt = __expf(lp - M);
    float z  = wgt;
    float a0 = wgt * ts.z;
    float a1 = wgt * ts.w;
    #pragma unroll
    for (int off = 32; off >= 1; off >>= 1) {
        z  += __shfl_xor(z,  off);
        a0 += __shfl_xor(a0, off);
        a1 += __shfl_xor(a1, off);
    }
    __syncthreads();                      // all reads of sred[][0] done
    if (lane == 0) { sred[wave][1] = z; sred[wave][2] = a0; sred[wave][3] = a1; }
    __syncthreads();

    if (t == 0) {
        float Z = 0.f, A0 = 0.f, A1 = 0.f;
        #pragma unroll
        for (int w = 0; w < 8; ++w) {
            Z  += sred[w][1];
            A0 += sred[w][2];
            A1 += sred[w][3];
        }
        out[b * 2 + 0] = fmaxf(A0 / Z + bm[0], 0.f);
        out[b * 2 + 1] = fmaxf(A1 / Z + bm[1], 0.f);
    }
}

extern "C" void kernel_launch(void* const* d_in, const int* in_sizes, int n_in,
                              void* d_out, int out_size, void* d_ws, size_t ws_size,
                              hipStream_t stream) {
    const int*   x   = (const int*)  d_in[0];
    const float* emb = (const float*)d_in[1];
    const float* Wq  = (const float*)d_in[2];
    const float* bq  = (const float*)d_in[3];
    const float* Wm  = (const float*)d_in[4];
    const float* bm  = (const float*)d_in[5];
    float* out  = (float*)d_out;
    float4* tab = (float4*)d_ws;          // 100000 * 16 B = 1.6 MB

    hipLaunchKernelGGL(precompute_tab, dim3((VOCAB + 63) / 64), dim3(1024), 0,
                       stream, emb, Wq, Wm, tab);
    hipLaunchKernelGGL(attn_out, dim3(BB), dim3(SS), 0, stream,
                       x, tab, bq, bm, out);
}